// Round 4
// baseline (312.226 us; speedup 1.0000x reference)
//
#include <hip/hip_runtime.h>

// out[b,n] = sum_{c,hw} x[b,c,hw] * W_s[n,hw] * W_d[n,c] + W_b[n]
// B=512, C=384, N=512, HW=169 (13x13).
//
// Fast path (needs ~76.5 MB workspace):
//   prep_x:  x (fp32) -> xp bf16 [b][ch=2][c][kk=96]  (k=ch*96+kk, zero pad)
//   prep_aux: W_s -> wsf bf16 in MFMA B-FRAGMENT ORDER [nm=32][kb=6][lane=64][8]
//             (lane q=lane>>4,m=lane&15 holds Ws[n=nm*16+m][k=kb*32+q*8+j]);
//             W_d -> WdT fp32 [c][n].
//   main (R4): 1-D grid 2048, swizzled so the 4 n-blocks of one b share an
//     XCD slot (id%8). Per block (b, n-tile 128): loop c-tiles(3) x chunks(2):
//     stage 24KB X chunk via global_load_lds linear copy (only thing behind
//     the barrier), B fragments loaded DIRECT global->VGPR from wsf (L2-hot,
//     no barrier), 16x16x32 bf16 MFMA; per c-tile fold acc*WdT into regs;
//     cross-wave LDS reduce + bias + coalesced store. No atomics, no memset.

#define B_   512
#define C_   384
#define N_   512
#define HW_  169
#define KCH  96
#define CT   128
#define NT   128

#define XP_ELEMS   ((size_t)B_ * 2 * C_ * KCH)     // 37,748,736
#define WSF_ELEMS  ((size_t)32 * 6 * 64 * 8)       // 98,304  (== 2*N_*KCH)
#define WDT_ELEMS  ((size_t)C_ * N_)               // 196,608

typedef __bf16 bf16x8 __attribute__((ext_vector_type(8)));
typedef float f32x4  __attribute__((ext_vector_type(4)));

__device__ __forceinline__ __bf16 f2bf(float f) {
  union { float f; unsigned u; } v; v.f = f;
  unsigned r = (v.u + 0x7FFFu + ((v.u >> 16) & 1u)) >> 16;   // RNE
  unsigned short s = (unsigned short)r;
  return __builtin_bit_cast(__bf16, s);
}

// ---------------- prepass kernels ----------------

// 8 elems/thread along k. grid: B*2*C*12/256 = 18432 blocks, exact.
__global__ __launch_bounds__(256)
void prep_x_kernel(const float* __restrict__ x, __bf16* __restrict__ xp) {
  int t = blockIdx.x * 256 + threadIdx.x;
  int kk8 = (t % 12) * 8;
  int t2  = t / 12;            // [b][ch][c]
  int c   = t2 % C_;
  int t3  = t2 / C_;
  int ch  = t3 & 1;
  int b   = t3 >> 1;
  const float* src = x + ((size_t)b * C_ + c) * HW_;
  int kbase = ch * KCH + kk8;
  bf16x8 v;
  #pragma unroll
  for (int j = 0; j < 8; ++j) {
    int k = kbase + j;
    float f = (k < HW_) ? src[k] : 0.f;
    v[j] = f2bf(f);
  }
  *(bf16x8*)(xp + (size_t)t * 8) = v;
}

// wsf: 12288 threads (one B-fragment 16B slot each); WdT: 196608 threads.
__global__ __launch_bounds__(256)
void prep_aux_kernel(const float* __restrict__ Ws,
                     const float* __restrict__ Wd,
                     __bf16* __restrict__ wsf,
                     float* __restrict__ WdT) {
  int t = blockIdx.x * 256 + threadIdx.x;
  if (t < 12288) {
    // t = (nm*6 + kb)*64 + lane
    int lane = t & 63;
    int fr   = t >> 6;         // nm*6 + kb
    int kb   = fr % 6;
    int nm   = fr / 6;
    int m    = lane & 15;
    int q    = lane >> 4;
    int n    = nm * 16 + m;
    int k0   = kb * 32 + q * 8;
    const float* src = Ws + (size_t)n * HW_;
    bf16x8 v;
    #pragma unroll
    for (int j = 0; j < 8; ++j) {
      int k = k0 + j;
      float f = (k < HW_) ? src[k] : 0.f;
      v[j] = f2bf(f);
    }
    *(bf16x8*)(wsf + (size_t)t * 8) = v;
  } else {
    int i = t - 12288;         // [c][n]
    if (i < C_ * N_) {
      int c = i >> 9;
      int n = i & (N_ - 1);
      WdT[i] = Wd[n * C_ + c];
    }
  }
}

// ---------------- fast main kernel ----------------

__global__ __launch_bounds__(256)
void conv_main_fast(const __bf16* __restrict__ xp,
                    const __bf16* __restrict__ wsf,
                    const float* __restrict__ WdT,   // [c][n]
                    const float* __restrict__ Wb,
                    float* __restrict__ out) {
  __shared__ __align__(16) __bf16 Xs[CT * KCH];   // 24 KB, linear image
  __shared__ float red[4][64];                     // 1 KB cross-wave reduce

  const int tid = threadIdx.x;
  // XCD-affinity swizzle: the 4 n-blocks of one b get ids equal mod 8.
  const int id   = blockIdx.x;           // 0..2047
  const int slot = id & 7;
  const int t8   = id >> 3;              // 0..255
  const int n_blk = t8 & 3;
  const int b     = (t8 >> 2) * 8 + slot;
  const int n0    = n_blk * NT;

  const int lane  = tid & 63;
  const int wv    = tid >> 6;          // 4 waves: 2x2 (c,n) 64x64 quadrants
  const int cq    = (wv >> 1) * 64;
  const int nq    = (wv & 1) * 64;
  const int lrow  = lane & 15;
  const int lquad = lane >> 4;
  const int nm0   = (n0 + nq) >> 4;    // base 16-n fragment row index

  float s[4] = {0.f, 0.f, 0.f, 0.f};   // per-lane partials for 4 n values

  for (int cb = 0; cb < 3; ++cb) {
    const f32x4 zero = {0.f, 0.f, 0.f, 0.f};
    f32x4 acc[4][4];
    #pragma unroll
    for (int mi = 0; mi < 4; ++mi)
      #pragma unroll
      for (int ni = 0; ni < 4; ++ni)
        acc[mi][ni] = zero;

    for (int ch = 0; ch < 2; ++ch) {
      const char* xsrc = (const char*)(xp + (((size_t)b * 2 + ch) * C_ + cb * CT) * KCH);
      char* xdst = (char*)Xs;

      __syncthreads();   // previous chunk's LDS reads complete before overwrite
      #pragma unroll
      for (int i = 0; i < 6; ++i) {
        const int j = i * 4 + wv;      // 24 x 1KB wave-instructions, linear copy
        __builtin_amdgcn_global_load_lds(
            (const __attribute__((address_space(1))) void*)(xsrc + j * 1024 + lane * 16),
            (__attribute__((address_space(3))) void*)(xdst + j * 1024),
            16, 0, 0);
      }
      __syncthreads();   // DMA drained (24 KB only) before fragment reads

      #pragma unroll
      for (int ks = 0; ks < 3; ++ks) {
        const int kb = ch * 3 + ks;
        const int kc = ks * 32 + lquad * 8;
        bf16x8 afr[4], bfr[4];
        #pragma unroll
        for (int mi = 0; mi < 4; ++mi)
          afr[mi] = *(const bf16x8*)&Xs[(cq + mi * 16 + lrow) * KCH + kc];
        // B fragments: direct global->VGPR, one coalesced dwordx4 per frag
        #pragma unroll
        for (int ni = 0; ni < 4; ++ni)
          bfr[ni] = *(const bf16x8*)(wsf + ((size_t)((nm0 + ni) * 6 + kb) * 64 + lane) * 8);
        #pragma unroll
        for (int mi = 0; mi < 4; ++mi)
          #pragma unroll
          for (int ni = 0; ni < 4; ++ni)
            acc[mi][ni] = __builtin_amdgcn_mfma_f32_16x16x32_bf16(
                afr[mi], bfr[ni], acc[mi][ni], 0, 0, 0);
      }
    }

    // fold this c-tile: s[ni] += sum_c P[c,n] * WdT[c,n]
    // C-layout: col(n) = lane&15, row(c) = (lane>>4)*4 + reg   [verified R1-R3]
    #pragma unroll
    for (int ni = 0; ni < 4; ++ni) {
      const int n = n0 + nq + ni * 16 + lrow;
      #pragma unroll
      for (int mi = 0; mi < 4; ++mi) {
        const int cbase = cb * CT + cq + mi * 16 + lquad * 4;
        #pragma unroll
        for (int i = 0; i < 4; ++i)
          s[ni] += acc[mi][ni][i] * WdT[(size_t)(cbase + i) * N_ + n];
      }
    }
  }

  // intra-wave: combine the 4 lane-quads (disjoint c subsets, same n)
  #pragma unroll
  for (int ni = 0; ni < 4; ++ni) {
    s[ni] += __shfl_xor(s[ni], 16, 64);
    s[ni] += __shfl_xor(s[ni], 32, 64);
  }
  if (lane < 16) {
    #pragma unroll
    for (int ni = 0; ni < 4; ++ni)
      red[wv][ni * 16 + lrow] = s[ni];
  }
  __syncthreads();

  // cross-wave: waves {0,2} share nq=0, {1,3} share nq=64 (disjoint c halves)
  if (tid < NT) {
    const int half = tid >> 6;
    const int idx  = tid & 63;
    const int n    = n0 + tid;
    float v = red[half][idx] + red[half + 2][idx] + Wb[n];
    out[(size_t)b * N_ + n] = v;
  }
}

// ---------------- fallback main kernel (no workspace needed) ----------------

#define LDSS 104

__global__ __launch_bounds__(256)
void conv_main_fallback(const float* __restrict__ x,
                        const float* __restrict__ Ws_g,
                        const float* __restrict__ Wd,
                        const float* __restrict__ Wb,
                        float* __restrict__ out) {
  __shared__ __align__(16) __bf16 Xs[CT][LDSS];
  __shared__ __align__(16) __bf16 Ws[NT][LDSS];

  const int tid   = threadIdx.x;
  const int n_blk = blockIdx.x;
  const int c_blk = blockIdx.y;
  const int b     = blockIdx.z;
  const int c0 = c_blk * CT;
  const int n0 = n_blk * NT;
  const int lane  = tid & 63;
  const int wv    = tid >> 6;
  const int cq    = (wv >> 1) * 64;
  const int nq    = (wv & 1) * 64;
  const int lrow  = lane & 15;
  const int lquad = lane >> 4;

  const f32x4 zero = {0.f, 0.f, 0.f, 0.f};
  f32x4 acc[4][4];
  #pragma unroll
  for (int mi = 0; mi < 4; ++mi)
    #pragma unroll
    for (int ni = 0; ni < 4; ++ni)
      acc[mi][ni] = zero;

  const float* xb  = x    + (size_t)b  * (C_ * HW_) + (size_t)c0 * HW_;
  const float* wsb = Ws_g + (size_t)n0 * HW_;

  for (int ch = 0; ch < 2; ++ch) {
    const int k0 = ch * KCH;
    __syncthreads();
    for (int e = tid; e < CT * KCH; e += 256) {
      int r   = e / KCH;
      int col = e - r * KCH;
      int k   = k0 + col;
      float vx = 0.f, vw = 0.f;
      if (k < HW_) {
        vx = xb [r * HW_ + k];
        vw = wsb[r * HW_ + k];
      }
      Xs[r][col] = f2bf(vx);
      Ws[r][col] = f2bf(vw);
    }
    __syncthreads();

    #pragma unroll
    for (int ks = 0; ks < 3; ++ks) {
      const int kc = ks * 32 + lquad * 8;
      bf16x8 afr[4], bfr[4];
      #pragma unroll
      for (int mi = 0; mi < 4; ++mi)
        afr[mi] = *(const bf16x8*)&Xs[cq + mi * 16 + lrow][kc];
      #pragma unroll
      for (int ni = 0; ni < 4; ++ni)
        bfr[ni] = *(const bf16x8*)&Ws[nq + ni * 16 + lrow][kc];
      #pragma unroll
      for (int mi = 0; mi < 4; ++mi)
        #pragma unroll
        for (int ni = 0; ni < 4; ++ni)
          acc[mi][ni] = __builtin_amdgcn_mfma_f32_16x16x32_bf16(
              afr[mi], bfr[ni], acc[mi][ni], 0, 0, 0);
    }
  }

  #pragma unroll
  for (int ni = 0; ni < 4; ++ni) {
    const int n = n0 + nq + ni * 16 + lrow;
    float sv = 0.f;
    #pragma unroll
    for (int mi = 0; mi < 4; ++mi) {
      const int cbase = c0 + cq + mi * 16 + lquad * 4;
      #pragma unroll
      for (int i = 0; i < 4; ++i)
        sv += acc[mi][ni][i] * Wd[(size_t)n * C_ + (cbase + i)];
    }
    sv += __shfl_xor(sv, 16, 64);
    sv += __shfl_xor(sv, 32, 64);
    if (lane < 16) {
      if (c_blk == 0 && cq == 0) sv += Wb[n];
      atomicAdd(&out[(size_t)b * N_ + n], sv);
    }
  }
}

extern "C" void kernel_launch(void* const* d_in, const int* in_sizes, int n_in,
                              void* d_out, int out_size, void* d_ws, size_t ws_size,
                              hipStream_t stream) {
  const float* x   = (const float*)d_in[0];   // [512,384,13,13]
  const float* Wsp = (const float*)d_in[1];   // [512,13,13]
  const float* Wd  = (const float*)d_in[2];   // [512,384]
  const float* Wb  = (const float*)d_in[3];   // [1,512]
  float* out = (float*)d_out;                 // [512,512] fp32

  const size_t need = (XP_ELEMS + WSF_ELEMS) * sizeof(__bf16)
                    + WDT_ELEMS * sizeof(float);

  if (ws_size >= need) {
    __bf16* xp  = (__bf16*)d_ws;
    __bf16* wsf = xp + XP_ELEMS;
    float*  wdT = (float*)(wsf + WSF_ELEMS);

    prep_x_kernel  <<<(int)(XP_ELEMS / 8 / 256), 256, 0, stream>>>(x, xp);
    prep_aux_kernel<<<(12288 + C_ * N_ + 255) / 256, 256, 0, stream>>>(Wsp, Wd, wsf, wdT);

    conv_main_fast<<<2048, 256, 0, stream>>>(xp, wsf, wdT, Wb, out);
  } else {
    hipMemsetAsync(d_out, 0, (size_t)out_size * sizeof(float), stream);
    dim3 grid(N_ / NT, C_ / CT, B_);
    conv_main_fallback<<<grid, 256, 0, stream>>>(x, Wsp, Wd, Wb, out);
  }
}

// Round 5
// 289.351 us; speedup vs baseline: 1.0791x; 1.0791x over previous
//
#include <hip/hip_runtime.h>

// out[b,n] = sum_{c,hw} x[b,c,hw] * W_s[n,hw] * W_d[n,c] + W_b[n]
// B=512, C=384, N=512, HW=169 (13x13).
//
// R5: barrier-free main kernel. Everything pre-swizzled into MFMA fragment
// order so the K-loop is pure {coalesced global load -> MFMA} with no LDS
// staging and no __syncthreads (ILP-pipelined by the compiler):
//   xf  bf16 [b][cm=24][kb=6][lane=64][8]   A-fragments (75.5 MB)
//   wsf bf16 [nm=32][kb=6][lane=64][8]      B-fragments (192 KB, L2-hot)
//   WdT fp32 [c][n]
// Grid 6144 = (b, n_blk 0..3, c_blk 0..2), XCD-swizzled so all 12 blocks of
// one b share an XCD (L2 locality for xf). Epilogue folds acc*WdT in regs,
// shfl + LDS cross-wave reduce, 1 atomicAdd per (block, n); bias by c_blk 0.

#define B_   512
#define C_   384
#define N_   512
#define HW_  169
#define CT   128
#define NT   128

#define XF_ELEMS   ((size_t)B_ * 24 * 6 * 64 * 8)  // 37,748,736 (75.5 MB)
#define WSF_ELEMS  ((size_t)32 * 6 * 64 * 8)       // 98,304
#define WDT_ELEMS  ((size_t)C_ * N_)               // 196,608

typedef __bf16 bf16x8 __attribute__((ext_vector_type(8)));
typedef float f32x4  __attribute__((ext_vector_type(4)));

__device__ __forceinline__ __bf16 f2bf(float f) {
  union { float f; unsigned u; } v; v.f = f;
  unsigned r = (v.u + 0x7FFFu + ((v.u >> 16) & 1u)) >> 16;   // RNE
  unsigned short s = (unsigned short)r;
  return __builtin_bit_cast(__bf16, s);
}

// ---------------- prepass kernels ----------------

// x -> A-fragment order, fully coalesced via LDS staging.
// Block = (b, g) with g indexing 64-c-row groups (C=384=6x64). Grid 3072,
// XCD-swizzled so b's blocks run on XCD b%8 (warm L2 for the main kernel).
__global__ __launch_bounds__(256)
void prep_xf_kernel(const float* __restrict__ x, __bf16* __restrict__ xf) {
  __shared__ float Xl[64][172];   // 169 cols + pad, 44 KB
  const int tid  = threadIdx.x;
  const int id   = blockIdx.x;
  const int slot = id & 7;
  const int q8   = id >> 3;        // 0..383
  const int g    = q8 % 6;
  const int b    = (q8 / 6) * 8 + slot;

  const float* src = x + ((size_t)b * C_ + g * 64) * HW_;
  for (int i = tid; i < 64 * HW_; i += 256) {      // coalesced dword loads
    int r  = i / HW_;
    int cl = i - r * HW_;
    Xl[r][cl] = src[i];
  }
  __syncthreads();

  // 1536 16B output slots: s = (cm_l*6 + kb)*64 + l
  #pragma unroll
  for (int p = 0; p < 6; ++p) {
    int s    = p * 256 + tid;
    int cm_l = s / 384;            // 0..3
    int rem  = s - cm_l * 384;
    int kb   = rem >> 6;           // 0..5
    int l    = rem & 63;
    int m    = l & 15;
    int q    = l >> 4;
    int row  = cm_l * 16 + m;
    int k0   = kb * 32 + q * 8;
    bf16x8 v;
    #pragma unroll
    for (int j = 0; j < 8; ++j) {
      int k = k0 + j;
      float f = (k < HW_) ? Xl[row][k] : 0.f;
      v[j] = f2bf(f);
    }
    *(bf16x8*)(xf + ((((size_t)b * 24 + g * 4 + cm_l) * 6 + kb) << 9) + (size_t)l * 8) = v;
  }
}

// wsf (B-fragment order) + WdT transpose. 816 blocks.
__global__ __launch_bounds__(256)
void prep_aux_kernel(const float* __restrict__ Ws,
                     const float* __restrict__ Wd,
                     __bf16* __restrict__ wsf,
                     float* __restrict__ WdT) {
  int t = blockIdx.x * 256 + threadIdx.x;
  if (t < 12288) {
    int lane = t & 63;
    int fr   = t >> 6;         // nm*6 + kb
    int kb   = fr % 6;
    int nm   = fr / 6;
    int m    = lane & 15;
    int q    = lane >> 4;
    int n    = nm * 16 + m;
    int k0   = kb * 32 + q * 8;
    const float* src = Ws + (size_t)n * HW_;
    bf16x8 v;
    #pragma unroll
    for (int j = 0; j < 8; ++j) {
      int k = k0 + j;
      float f = (k < HW_) ? src[k] : 0.f;
      v[j] = f2bf(f);
    }
    *(bf16x8*)(wsf + (size_t)t * 8) = v;
  } else {
    int i = t - 12288;         // [c][n]
    if (i < C_ * N_) {
      int c = i >> 9;
      int n = i & (N_ - 1);
      WdT[i] = Wd[n * C_ + c];
    }
  }
}

// ---------------- fast main kernel (barrier-free K-loop) ----------------

__global__ __launch_bounds__(256)
void conv_main_fast(const __bf16* __restrict__ xf,
                    const __bf16* __restrict__ wsf,
                    const float* __restrict__ WdT,   // [c][n]
                    const float* __restrict__ Wb,
                    float* __restrict__ out) {
  __shared__ float red[4][64];     // 1 KB cross-wave reduce only

  const int tid  = threadIdx.x;
  // XCD swizzle: all 12 (n_blk,c_blk) blocks of one b share slot = b%8.
  const int id   = blockIdx.x;     // 0..6143
  const int slot = id & 7;
  const int grp  = id >> 3;        // 0..767
  const int sub  = grp % 12;       // n_blk*3 + c_blk
  const int b    = (grp / 12) * 8 + slot;
  const int n_blk = sub / 3;
  const int c_blk = sub % 3;
  const int n0    = n_blk * NT;

  const int lane  = tid & 63;
  const int wv    = tid >> 6;          // 4 waves: 2x2 (c,n) 64x64 quadrants
  const int cq    = (wv >> 1) * 64;
  const int nq    = (wv & 1) * 64;
  const int lrow  = lane & 15;
  const int lquad = lane >> 4;

  const int nm0 = (n0 + nq) >> 4;            // global 16-n fragment row
  const int cm0 = c_blk * 8 + (cq >> 4);     // global 16-c fragment row

  const __bf16* abase = xf + (((size_t)b * 24 + cm0) * 6) * 512 + (size_t)lane * 8;
  const __bf16* bbase = wsf + ((size_t)nm0 * 6) * 512 + (size_t)lane * 8;

  const f32x4 zero = {0.f, 0.f, 0.f, 0.f};
  f32x4 acc[4][4];
  #pragma unroll
  for (int mi = 0; mi < 4; ++mi)
    #pragma unroll
    for (int ni = 0; ni < 4; ++ni)
      acc[mi][ni] = zero;

  // Pure load->MFMA stream; no barriers, no LDS. 48 coalesced dwordx4 loads,
  // 96 MFMA per wave, compiler-pipelined.
  #pragma unroll
  for (int kb = 0; kb < 6; ++kb) {
    bf16x8 afr[4], bfr[4];
    #pragma unroll
    for (int mi = 0; mi < 4; ++mi)
      afr[mi] = *(const bf16x8*)(abase + ((size_t)mi * 6 + kb) * 512);
    #pragma unroll
    for (int ni = 0; ni < 4; ++ni)
      bfr[ni] = *(const bf16x8*)(bbase + ((size_t)ni * 6 + kb) * 512);
    #pragma unroll
    for (int mi = 0; mi < 4; ++mi)
      #pragma unroll
      for (int ni = 0; ni < 4; ++ni)
        acc[mi][ni] = __builtin_amdgcn_mfma_f32_16x16x32_bf16(
            afr[mi], bfr[ni], acc[mi][ni], 0, 0, 0);
  }

  // Fold: s[ni] = sum_c P[c,n] * WdT[c,n] for this block's 128-c slice.
  // C-layout: col(n) = lane&15, row(c) = (lane>>4)*4 + reg   [verified R1-R4]
  float s[4] = {0.f, 0.f, 0.f, 0.f};
  #pragma unroll
  for (int ni = 0; ni < 4; ++ni) {
    const int n = n0 + nq + ni * 16 + lrow;
    #pragma unroll
    for (int mi = 0; mi < 4; ++mi) {
      const int cbase = c_blk * CT + cq + mi * 16 + lquad * 4;
      #pragma unroll
      for (int i = 0; i < 4; ++i)
        s[ni] += acc[mi][ni][i] * WdT[(size_t)(cbase + i) * N_ + n];
    }
  }

  // intra-wave quad combine (disjoint c, same n)
  #pragma unroll
  for (int ni = 0; ni < 4; ++ni) {
    s[ni] += __shfl_xor(s[ni], 16, 64);
    s[ni] += __shfl_xor(s[ni], 32, 64);
  }
  if (lane < 16) {
    #pragma unroll
    for (int ni = 0; ni < 4; ++ni)
      red[wv][ni * 16 + lrow] = s[ni];
  }
  __syncthreads();

  // cross-wave: waves {0,2} share nq=0, {1,3} share nq=64 (disjoint c halves)
  if (tid < NT) {
    const int half = tid >> 6;
    const int idx  = tid & 63;
    const int n    = n0 + tid;
    float v = red[half][idx] + red[half + 2][idx];
    if (c_blk == 0) v += Wb[n];           // bias exactly once per (b,n)
    atomicAdd(&out[(size_t)b * N_ + n], v);
  }
}

// ---------------- fallback main kernel (no workspace needed) ----------------

#define LDSS 104
#define KCH  96

__global__ __launch_bounds__(256)
void conv_main_fallback(const float* __restrict__ x,
                        const float* __restrict__ Ws_g,
                        const float* __restrict__ Wd,
                        const float* __restrict__ Wb,
                        float* __restrict__ out) {
  __shared__ __align__(16) __bf16 Xs[CT][LDSS];
  __shared__ __align__(16) __bf16 Ws[NT][LDSS];

  const int tid   = threadIdx.x;
  const int n_blk = blockIdx.x;
  const int c_blk = blockIdx.y;
  const int b     = blockIdx.z;
  const int c0 = c_blk * CT;
  const int n0 = n_blk * NT;
  const int lane  = tid & 63;
  const int wv    = tid >> 6;
  const int cq    = (wv >> 1) * 64;
  const int nq    = (wv & 1) * 64;
  const int lrow  = lane & 15;
  const int lquad = lane >> 4;

  const f32x4 zero = {0.f, 0.f, 0.f, 0.f};
  f32x4 acc[4][4];
  #pragma unroll
  for (int mi = 0; mi < 4; ++mi)
    #pragma unroll
    for (int ni = 0; ni < 4; ++ni)
      acc[mi][ni] = zero;

  const float* xb  = x    + (size_t)b  * (C_ * HW_) + (size_t)c0 * HW_;
  const float* wsb = Ws_g + (size_t)n0 * HW_;

  for (int ch = 0; ch < 2; ++ch) {
    const int k0 = ch * KCH;
    __syncthreads();
    for (int e = tid; e < CT * KCH; e += 256) {
      int r   = e / KCH;
      int col = e - r * KCH;
      int k   = k0 + col;
      float vx = 0.f, vw = 0.f;
      if (k < HW_) {
        vx = xb [r * HW_ + k];
        vw = wsb[r * HW_ + k];
      }
      Xs[r][col] = f2bf(vx);
      Ws[r][col] = f2bf(vw);
    }
    __syncthreads();

    #pragma unroll
    for (int ks = 0; ks < 3; ++ks) {
      const int kc = ks * 32 + lquad * 8;
      bf16x8 afr[4], bfr[4];
      #pragma unroll
      for (int mi = 0; mi < 4; ++mi)
        afr[mi] = *(const bf16x8*)&Xs[cq + mi * 16 + lrow][kc];
      #pragma unroll
      for (int ni = 0; ni < 4; ++ni)
        bfr[ni] = *(const bf16x8*)&Ws[nq + ni * 16 + lrow][kc];
      #pragma unroll
      for (int mi = 0; mi < 4; ++mi)
        #pragma unroll
        for (int ni = 0; ni < 4; ++ni)
          acc[mi][ni] = __builtin_amdgcn_mfma_f32_16x16x32_bf16(
              afr[mi], bfr[ni], acc[mi][ni], 0, 0, 0);
    }
  }

  #pragma unroll
  for (int ni = 0; ni < 4; ++ni) {
    const int n = n0 + nq + ni * 16 + lrow;
    float sv = 0.f;
    #pragma unroll
    for (int mi = 0; mi < 4; ++mi) {
      const int cbase = c0 + cq + mi * 16 + lquad * 4;
      #pragma unroll
      for (int i = 0; i < 4; ++i)
        sv += acc[mi][ni][i] * Wd[(size_t)n * C_ + (cbase + i)];
    }
    sv += __shfl_xor(sv, 16, 64);
    sv += __shfl_xor(sv, 32, 64);
    if (lane < 16) {
      if (c_blk == 0 && cq == 0) sv += Wb[n];
      atomicAdd(&out[(size_t)b * N_ + n], sv);
    }
  }
}

extern "C" void kernel_launch(void* const* d_in, const int* in_sizes, int n_in,
                              void* d_out, int out_size, void* d_ws, size_t ws_size,
                              hipStream_t stream) {
  const float* x   = (const float*)d_in[0];   // [512,384,13,13]
  const float* Wsp = (const float*)d_in[1];   // [512,13,13]
  const float* Wd  = (const float*)d_in[2];   // [512,384]
  const float* Wb  = (const float*)d_in[3];   // [1,512]
  float* out = (float*)d_out;                 // [512,512] fp32

  hipMemsetAsync(d_out, 0, (size_t)out_size * sizeof(float), stream);

  const size_t need = (XF_ELEMS + WSF_ELEMS) * sizeof(__bf16)
                    + WDT_ELEMS * sizeof(float);

  if (ws_size >= need) {
    __bf16* xf  = (__bf16*)d_ws;
    __bf16* wsf = xf + XF_ELEMS;
    float*  wdT = (float*)(wsf + WSF_ELEMS);

    prep_aux_kernel<<<(12288 + C_ * N_ + 255) / 256, 256, 0, stream>>>(Wsp, Wd, wsf, wdT);
    prep_xf_kernel <<<3072, 256, 0, stream>>>(x, xf);

    conv_main_fast<<<6144, 256, 0, stream>>>(xf, wsf, wdT, Wb, out);
  } else {
    dim3 grid(N_ / NT, C_ / CT, B_);
    conv_main_fallback<<<grid, 256, 0, stream>>>(x, Wsp, Wd, Wb, out);
  }
}